// Round 6
// baseline (903.623 us; speedup 1.0000x reference)
//
#include <hip/hip_runtime.h>
#include <math.h>

// Problem constants
#define DIN   4096
#define NST   16
#define RR    128
#define LSEQ  2048
#define NTOK  4096   // B*L
#define BB    2
#define CHUNK 64
#define NCH   (LSEQ / CHUNK)   // 32
#define KSPL  8                // k-split for skinny GEMM
#define KC    (DIN / KSPL)     // 512

typedef __attribute__((ext_vector_type(8))) short short8;
typedef __attribute__((ext_vector_type(4))) float f32x4;

__device__ __forceinline__ float sigmoidf_(float x) { return 1.f / (1.f + __expf(-x)); }
__device__ __forceinline__ float softplusf_(float x) {
    return fmaxf(x, 0.f) + log1pf(__expf(-fabsf(x)));
}
__device__ __forceinline__ unsigned short f2bf_(float f) {
    unsigned u = __float_as_uint(f);
    return (unsigned short)((u + 0x7FFFu + ((u >> 16) & 1u)) >> 16);   // RNE
}
__device__ __forceinline__ void gld_lds16_(const unsigned short* g, unsigned short* l) {
    __builtin_amdgcn_global_load_lds((const __attribute__((address_space(1))) unsigned int*)g,
                                     (__attribute__((address_space(3))) unsigned int*)l,
                                     16, 0, 0);
}

// fp32 -> bf16 (RNE), 8 elements/thread
__global__ __launch_bounds__(256)
void f2bf_kernel(const float* __restrict__ src, unsigned short* __restrict__ dst, int n8)
{
    int i = blockIdx.x * 256 + threadIdx.x;
    if (i >= n8) return;
    const float4* s = (const float4*)src + 2 * (size_t)i;
    float4 a = s[0], b = s[1];
    union { unsigned short u[8]; uint4 v; } o;
    o.u[0] = f2bf_(a.x); o.u[1] = f2bf_(a.y); o.u[2] = f2bf_(a.z); o.u[3] = f2bf_(a.w);
    o.u[4] = f2bf_(b.x); o.u[5] = f2bf_(b.y); o.u[6] = f2bf_(b.z); o.u[7] = f2bf_(b.w);
    ((uint4*)dst)[i] = o.v;
}

// dst += src, float4-vectorized (split-K reduce for GEMM3)
__global__ __launch_bounds__(256)
void add_f4_kernel(float* __restrict__ dst, const float* __restrict__ src, int n4)
{
    int i = blockIdx.x * 256 + threadIdx.x;
    if (i >= n4) return;
    float4 a = ((const float4*)dst)[i];
    float4 b = ((const float4*)src)[i];
    a.x += b.x; a.y += b.y; a.z += b.z; a.w += b.w;
    ((float4*)dst)[i] = a;
}

// ---- 256x256 8-phase bf16 MFMA GEMM ---------------------------------------
// C[M,N] fp32 = A[M,K] * W[N,K]^T.  BM=BN=256, BK=64, 8 waves (2Mx4N),
// per-wave 128x64 output, 128 KiB double-buffered LDS, 3-bit LDS swizzle
// (0 bank conflicts, R3-verified), counted vmcnt(6), setprio, 2-D XCD chunk.
// R6: group-clustered reads + register double-buffer. All 24 fragment reads
// of a buffer issue at the FIRST phase of its 4-phase group into 4 disjoint
// reg sets (aF=A-low, aG=A-high, bA=B-low32, bB=B-high32); no manual lgkm
// waits — the compiler emits minimal counted lgkmcnt before each MFMA quad,
// so the LDS drain of later quads overlaps earlier quads' MFMA execution.
// One barrier per phase boundary. Hazard ledger (cross-wave, single-barrier):
//   stage B0(h0)@P3 needs all waves' bA,bB drained: bB waited before Q(0,1)@P2
//     -> guaranteed at P2-close BAR (= P3 open).  [bA earlier, P1]
//   stage A0(h0)+B1(h1)@P4 needs aF,aG,bB drained: aG waited before Q(1,1)@P3
//     -> P3-close BAR.
//   stage A1(h1)@P5 needs aG drained (P3) -> P4-close BAR.
//   stage buf1.A1@P1 needs prev-group aG drained (P7) -> P8-close BAR.
//   buf-swap reads: buf1 valid after P4 vmcnt(6)+BAR (drains prevP7, prevP8,
//   P1 stages -> leaves P3+P4 = 6); buf0 valid after P8 vmcnt(6)+BAR. Same
//   checkpoints as the R3-verified schedule.
// MODE 0: plain. MODE 2: split dest at col DIN -> C2. MODE 3: split-K=2
// (virtual bm rows 0-15 -> k-half 0 -> C, 16-31 -> k-half 1 -> C2).

#define BAR()        asm volatile("s_barrier" ::: "memory")
#define WAIT_VM(n)   asm volatile("s_waitcnt vmcnt(" #n ")" ::: "memory")

// LDS layout (bytes): [0,32K) buf0.A  [32K,64K) buf0.B  [64K,96K) buf1.A  [96K,128K) buf1.B
// A/B region: 256 rows x 64 cols bf16, row stride 128 B, halves of 128 rows (16 KiB).
// Physical col_byte = logical col_byte ^ ((row&7)<<4).  Logical col for a
// fragment read = q*16 + ks*64; per-lane bases co0 (ks=0), co1 = co0^64 (ks=1).

#define RD_A0(P) do { _Pragma("unroll") \
  for (int ii = 0; ii < 4; ++ii) { \
      aF[ii][0] = *(const short8*)((P) + ii*2048 + co0); \
      aF[ii][1] = *(const short8*)((P) + ii*2048 + co1); } } while (0)

#define RD_A1(P) do { _Pragma("unroll") \
  for (int ii = 0; ii < 4; ++ii) { \
      aG[ii][0] = *(const short8*)((P) + 8192 + ii*2048 + co0); \
      aG[ii][1] = *(const short8*)((P) + 8192 + ii*2048 + co1); } } while (0)

#define RD_B0(P) do { _Pragma("unroll") \
  for (int jj = 0; jj < 2; ++jj) { \
      bA[jj][0] = *(const short8*)((P) + jj*2048 + co0); \
      bA[jj][1] = *(const short8*)((P) + jj*2048 + co1); } } while (0)

#define RD_B1(P) do { _Pragma("unroll") \
  for (int jj = 0; jj < 2; ++jj) { \
      bB[jj][0] = *(const short8*)((P) + 4096 + jj*2048 + co0); \
      bB[jj][1] = *(const short8*)((P) + 4096 + jj*2048 + co1); } } while (0)

#define MFMA_Q(AF, mh, BF, nh) do { __builtin_amdgcn_s_setprio(1); _Pragma("unroll") \
  for (int ii = 0; ii < 4; ++ii) { _Pragma("unroll") \
    for (int jj = 0; jj < 2; ++jj) { _Pragma("unroll") \
      for (int ks = 0; ks < 2; ++ks) \
        acc[(mh)*4+ii][(nh)*2+jj] = __builtin_amdgcn_mfma_f32_16x16x32_bf16( \
            AF[ii][ks], BF[jj][ks], acc[(mh)*4+ii][(nh)*2+jj], 0, 0, 0); } } \
  __builtin_amdgcn_s_setprio(0); } while (0)

// stage one 16B/lane load: half h (128 rows), part l (64 rows), K-tile `tile`
#define STGLD(gbase, sbase, h, l, tile) \
  gld_lds16_(gbase + (size_t)((h)*128 + (l)*64) * K + (size_t)(tile)*64, \
             (unsigned short*)(sbase + (h)*16384 + (l)*8192))

// One main-loop iteration: consumes K-tiles t (buf0, P1-4) and t+1 (buf1, P5-8).
// Staging:  P1: buf1.A1<-t+1 | P3: buf0.B0<-t+2 | P4: buf0.{A0,B1}<-t+2
//           P5: buf0.A1<-t+2 | P7: buf1.B0<-t+3 | P8: buf1.{A0,B1}<-t+3
#define ITER(t, PREF) do { \
  /* P1: stage; read ALL of buf0; Q(0,0) */ \
  STGLD(gA0, sA1, 1, 0, (t)+1); STGLD(gA0, sA1, 1, 1, (t)+1); \
  RD_A0(pA0); RD_B0(pB0c); RD_B1(pB0c); RD_A1(pA0); \
  MFMA_Q(aF, 0, bA, 0); \
  BAR(); \
  /* P2 */ \
  MFMA_Q(aF, 0, bB, 1); \
  BAR(); \
  /* P3 */ \
  if (PREF) { STGLD(gB0, sB0, 0, 0, (t)+2); STGLD(gB0, sB0, 0, 1, (t)+2); } \
  MFMA_Q(aG, 1, bB, 1); \
  BAR(); \
  /* P4: K-tile checkpoint */ \
  if (PREF) { STGLD(gA0, sA0, 0, 0, (t)+2); STGLD(gA0, sA0, 0, 1, (t)+2); \
              STGLD(gB0, sB0, 1, 0, (t)+2); STGLD(gB0, sB0, 1, 1, (t)+2); } \
  MFMA_Q(aG, 1, bA, 0); \
  if (PREF) { WAIT_VM(6); } else { WAIT_VM(0); } \
  BAR(); \
  /* P5: stage; read ALL of buf1; Q(0,0) */ \
  if (PREF) { STGLD(gA0, sA0, 1, 0, (t)+2); STGLD(gA0, sA0, 1, 1, (t)+2); } \
  RD_A0(pA1); RD_B0(pB1c); RD_B1(pB1c); RD_A1(pA1); \
  MFMA_Q(aF, 0, bA, 0); \
  BAR(); \
  /* P6 */ \
  MFMA_Q(aF, 0, bB, 1); \
  BAR(); \
  /* P7 */ \
  if (PREF) { STGLD(gB0, sB1, 0, 0, (t)+3); STGLD(gB0, sB1, 0, 1, (t)+3); } \
  MFMA_Q(aG, 1, bB, 1); \
  BAR(); \
  /* P8: K-tile checkpoint */ \
  if (PREF) { STGLD(gA0, sA1, 0, 0, (t)+3); STGLD(gA0, sA1, 0, 1, (t)+3); \
              STGLD(gB0, sB1, 1, 0, (t)+3); STGLD(gB0, sB1, 1, 1, (t)+3); } \
  MFMA_Q(aG, 1, bA, 0); \
  if (PREF) { WAIT_VM(6); } else { WAIT_VM(0); } \
  BAR(); \
} while (0)

// K = leading dim (row stride) of A/W; KL = K-extent this block accumulates.
template<int MODE>
__global__ __launch_bounds__(512)
void gemm256(const unsigned short* __restrict__ A, const unsigned short* __restrict__ W,
             float* __restrict__ C, int K, int KL, int ldc, float* __restrict__ C2,
             int nbx, int fx)
{
    __shared__ __align__(16) unsigned short sm[65536];   // 128 KiB
    char* smb = (char*)sm;

    const int tid = threadIdx.x;
    const int ln  = tid & 63;
    const int wv  = tid >> 6;     // 0..7
    const int wm  = wv >> 2;      // 0..1  (M direction)
    const int wn  = wv & 3;       // 0..3  (N direction)
    const int m15 = ln & 15;
    const int q   = ln >> 4;

    // 2-D XCD chunking (requires gridDim.x % 8 == 0, nbx % fx == 0)
    const int bid = blockIdx.x;
    const int xcd = bid & 7;
    const int idx = bid >> 3;
    const int cw  = nbx / fx;                  // region width in bn-blocks
    const int chh = (gridDim.x >> 3) / cw;     // region height in bm-blocks
    const int bn_i = (xcd % fx) * cw  + idx % cw;
    int bm_i = (xcd / fx) * chh + idx / cw;
    int kh = 0;
    if (MODE == 3) { kh = bm_i >> 4; bm_i &= 15; }   // split-K=2 (16 bm-blocks/half)
    const int bm  = bm_i << 8;
    const int bn  = bn_i << 8;

    // ds_read bases: 3-bit row swizzle, XOR'd column bases for ks=0/1
    const int co0 = (q * 16) ^ ((m15 & 7) << 4);
    const int co1 = co0 ^ 64;
    const int ra_base = wm * 16384 + m15 * 128;
    const int rb_base = wn * 8192  + m15 * 128;
    const char* pA0  = smb + ra_base;
    const char* pA1  = smb + 65536 + ra_base;
    const char* pB0c = smb + 32768 + rb_base;
    const char* pB1c = smb + 98304 + rb_base;

    // staging: linear LDS dest (base + lane*16), inverse-swizzled global source
    char* sA0 = smb +          tid * 16;
    char* sB0 = smb + 32768  + tid * 16;
    char* sA1 = smb + 65536  + tid * 16;
    char* sB1 = smb + 98304  + tid * 16;
    const int srow  = tid >> 3;                                   // 0..63
    const int secol = (((tid & 7) ^ ((tid >> 3) & 7)) * 8);       // logical col elems
    const unsigned short* gA0 = A + (size_t)(bm + srow) * K + secol + (size_t)kh * KL;
    const unsigned short* gB0 = W + (size_t)(bn + srow) * K + secol + (size_t)kh * KL;

    f32x4  acc[8][4] = {};
    short8 aF[4][2], aG[4][2], bA[2][2], bB[2][2];

    const int KT = KL >> 6;   // K-tiles of 64

    // Prologue: tile0 full (8 loads) + tile1 {A0,B0,B1} (6 loads); drain to 6.
    // (vmcnt(6) drains exactly the 8 tile0 loads -> buf0 valid for P1 reads.)
    STGLD(gA0, sA0, 0, 0, 0); STGLD(gA0, sA0, 0, 1, 0);
    STGLD(gA0, sA0, 1, 0, 0); STGLD(gA0, sA0, 1, 1, 0);
    STGLD(gB0, sB0, 0, 0, 0); STGLD(gB0, sB0, 0, 1, 0);
    STGLD(gB0, sB0, 1, 0, 0); STGLD(gB0, sB0, 1, 1, 0);
    STGLD(gA0, sA1, 0, 0, 1); STGLD(gA0, sA1, 0, 1, 1);
    STGLD(gB0, sB1, 0, 0, 1); STGLD(gB0, sB1, 0, 1, 1);
    STGLD(gB0, sB1, 1, 0, 1); STGLD(gB0, sB1, 1, 1, 1);
    WAIT_VM(6);
    BAR();

    for (int t = 0; t < KT - 2; t += 2) ITER(t, 1);
    ITER(KT - 2, 0);   // last pair: drains vmcnt at P4/P8

    // Epilogue (C/D map: col = m15-based, row = q*4+r — proven m97 mapping)
    float* Cp = C;
    int bcol = bn;
    if (MODE == 2 && bcol >= DIN) { Cp = C2; bcol -= DIN; }   // block-uniform
    if (MODE == 3 && kh) Cp = C2;                              // split-K partial
    #pragma unroll
    for (int i = 0; i < 8; ++i) {
        int row = bm + wm * 128 + i * 16 + q * 4;
        #pragma unroll
        for (int j = 0; j < 4; ++j) {
            int col = bcol + wn * 64 + j * 16 + m15;
            #pragma unroll
            for (int r = 0; r < 4; ++r)
                Cp[(size_t)(row + r) * ldc + col] = acc[i][j][r];
        }
    }
}

// ---- legacy 128x128 m97-structure MFMA GEMM (kept for the K=128 delta GEMM) --
// MODE 1: C = softplus(C + bias[col]).
template<int MODE>
__global__ __launch_bounds__(256)
void gemm_mfma_bt(const unsigned short* __restrict__ A, const unsigned short* __restrict__ W,
                  float* __restrict__ C, int K, int ldc,
                  const float* __restrict__ bias, float* __restrict__ C2)
{
    __shared__ unsigned short As[128 * 32];
    __shared__ unsigned short Ws[128 * 32];
    const int tid = threadIdx.x;
    const int bm = blockIdx.y << 7;
    int bn = blockIdx.x << 7;

    const int c0 = tid, c1 = tid + 256;
    const unsigned short* ga0 = A + (size_t)(bm + (c0 >> 2)) * K + (c0 & 3) * 8;
    const unsigned short* ga1 = A + (size_t)(bm + (c1 >> 2)) * K + (c1 & 3) * 8;
    const unsigned short* gw0 = W + (size_t)(bn + (c0 >> 2)) * K + (c0 & 3) * 8;
    const unsigned short* gw1 = W + (size_t)(bn + (c1 >> 2)) * K + (c1 & 3) * 8;
    unsigned short* la0 = &As[c0 * 8];
    unsigned short* la1 = &As[c1 * 8];
    unsigned short* lw0 = &Ws[c0 * 8];
    unsigned short* lw1 = &Ws[c1 * 8];

    const int ln  = tid & 63;
    const int wv  = tid >> 6;
    const int wm  = (wv >> 1) << 6;
    const int wn  = (wv & 1) << 6;
    const int m15 = ln & 15;
    const int q   = ln >> 4;

    f32x4 acc[4][4] = {};

    for (int k0 = 0; k0 < K; k0 += 32) {
        __syncthreads();
        gld_lds16_(ga0, la0); gld_lds16_(ga1, la1);
        gld_lds16_(gw0, lw0); gld_lds16_(gw1, lw1);
        ga0 += 32; ga1 += 32; gw0 += 32; gw1 += 32;
        __syncthreads();
        short8 af[4], wf[4];
        #pragma unroll
        for (int i = 0; i < 4; ++i)
            af[i] = *(const short8*)&As[(wm + i * 16 + m15) * 32 + q * 8];
        #pragma unroll
        for (int j = 0; j < 4; ++j)
            wf[j] = *(const short8*)&Ws[(wn + j * 16 + m15) * 32 + q * 8];
        #pragma unroll
        for (int i = 0; i < 4; ++i)
            #pragma unroll
            for (int j = 0; j < 4; ++j)
                acc[i][j] = __builtin_amdgcn_mfma_f32_16x16x32_bf16(af[i], wf[j],
                                                                    acc[i][j], 0, 0, 0);
    }

    float* Cp = C;
    if (MODE == 2 && bn >= DIN) { Cp = C2; bn -= DIN; }

    #pragma unroll
    for (int i = 0; i < 4; ++i)
        #pragma unroll
        for (int j = 0; j < 4; ++j) {
            int col = bn + wn + j * 16 + m15;
            #pragma unroll
            for (int r = 0; r < 4; ++r) {
                int row = bm + wm + i * 16 + q * 4 + r;
                float v = acc[i][j][r];
                if (MODE == 1) v = softplusf_(v + bias[col]);
                Cp[(size_t)row * ldc + col] = v;
            }
        }
}

// ---- K-split skinny GEMM: partial[kspl][M][160] = A[M, kc] * W[160, kc]^T --
__global__ __launch_bounds__(256)
void gemm_kspl_kernel(const float* __restrict__ A, const float* __restrict__ W,
                      float* __restrict__ partial)
{
    __shared__ float As[16][66];
    __shared__ float Ws[16][162];
    const int tid = threadIdx.x;
    const int tx = tid & 15;
    const int ty = tid >> 4;
    const int bm = blockIdx.x << 6;
    const int k0 = blockIdx.y * KC;

    float acc[4][10] = {};

    for (int kt = 0; kt < KC; kt += 16) {
        float2 a2[2];
        #pragma unroll
        for (int i = 0; i < 2; ++i) {
            int idx = tid + 256 * i;
            int row = idx >> 3, kofs = (idx & 7) * 2;
            a2[i] = *(const float2*)&A[(size_t)(bm + row) * DIN + k0 + kt + kofs];
        }
        float2 w2[5];
        #pragma unroll
        for (int i = 0; i < 5; ++i) {
            int idx = tid + 256 * i;
            int wrow = idx >> 3, wk = (idx & 7) * 2;
            w2[i] = *(const float2*)&W[(size_t)wrow * DIN + k0 + kt + wk];
        }
        __syncthreads();
        #pragma unroll
        for (int i = 0; i < 2; ++i) {
            int idx = tid + 256 * i;
            int row = idx >> 3, kofs = (idx & 7) * 2;
            As[kofs][row] = a2[i].x; As[kofs + 1][row] = a2[i].y;
        }
        #pragma unroll
        for (int i = 0; i < 5; ++i) {
            int idx = tid + 256 * i;
            int wrow = idx >> 3, wk = (idx & 7) * 2;
            Ws[wk][wrow] = w2[i].x; Ws[wk + 1][wrow] = w2[i].y;
        }
        __syncthreads();
        #pragma unroll
        for (int kk = 0; kk < 16; ++kk) {
            float2 av0 = *(const float2*)&As[kk][ty * 4];
            float2 av1 = *(const float2*)&As[kk][ty * 4 + 2];
            float a[4] = {av0.x, av0.y, av1.x, av1.y};
            float w[10];
            #pragma unroll
            for (int j = 0; j < 5; ++j) {
                float2 wv = *(const float2*)&Ws[kk][tx * 10 + 2 * j];
                w[2 * j] = wv.x; w[2 * j + 1] = wv.y;
            }
            #pragma unroll
            for (int i = 0; i < 4; ++i)
                #pragma unroll
                for (int j = 0; j < 10; ++j)
                    acc[i][j] = fmaf(a[i], w[j], acc[i][j]);
        }
        __syncthreads();
    }

    float* po = partial + (size_t)blockIdx.y * NTOK * 160;
    #pragma unroll
    for (int i = 0; i < 4; ++i) {
        int r = bm + ty * 4 + i;
        #pragma unroll
        for (int j = 0; j < 5; ++j)
            *(float2*)&po[(size_t)r * 160 + tx * 10 + 2 * j] =
                make_float2(acc[i][2 * j], acc[i][2 * j + 1]);
    }
}

// sum KSPL partials -> xdbl; also emit bf16 copy of dt_r (cols < 128)
__global__ __launch_bounds__(256)
void kspl_reduce_kernel(const float* __restrict__ partial, float* __restrict__ xdbl,
                        unsigned short* __restrict__ dtr)
{
    int idx = blockIdx.x * 256 + threadIdx.x;   // over NTOK*160
    float s = 0.f;
    #pragma unroll
    for (int k = 0; k < KSPL; ++k)
        s += partial[(size_t)k * NTOK * 160 + idx];
    xdbl[idx] = s;
    int row = idx / 160;
    int col = idx - row * 160;
    if (col < RR) dtr[(size_t)row * RR + col] = f2bf_(s);
}

// Causal depthwise conv (K=4) + SiLU.
__global__ __launch_bounds__(256)
void conv_silu_kernel(const float* __restrict__ x, const float* __restrict__ cw,
                      float* __restrict__ xc)
{
    int idx = blockIdx.x * 256 + threadIdx.x;
    int d = idx & (DIN - 1);
    int tok = idx >> 12;
    int t = tok & (LSEQ - 1);
    float w0 = cw[d * 4 + 0], w1 = cw[d * 4 + 1];
    float w2 = cw[d * 4 + 2], w3 = cw[d * 4 + 3];
    const float* xp = x + (size_t)tok * DIN + d;
    float acc = w3 * xp[0];
    if (t >= 1) acc = fmaf(w2, xp[-DIN], acc);
    if (t >= 2) acc = fmaf(w1, xp[-2 * DIN], acc);
    if (t >= 3) acc = fmaf(w0, xp[-3 * DIN], acc);
    xc[idx] = acc * sigmoidf_(acc);
}

// ---- Chunked parallel selective scan --------------------------------------
__global__ __launch_bounds__(256)
void scan_part1_kernel(const float* __restrict__ delta, const float* __restrict__ xc,
                       const float* __restrict__ xdbl, const float* __restrict__ A_log,
                       float* __restrict__ hloc, float* __restrict__ ssum)
{
    int d = blockIdx.x * 256 + threadIdx.x;
    int c = blockIdx.y;
    int b = blockIdx.z;
    float A[NST], h[NST];
    #pragma unroll
    for (int n = 0; n < NST; ++n) {
        A[n] = -__expf(A_log[d * NST + n]);
        h[n] = 0.f;
    }
    float s = 0.f;
    int tok = b * LSEQ + c * CHUNK;
    for (int t = 0; t < CHUNK; ++t, ++tok) {
        float dv = delta[(size_t)tok * DIN + d];
        float xv = xc[(size_t)tok * DIN + d];
        const float* bc = xdbl + (size_t)tok * 160 + RR;
        float dx = dv * xv;
        s += dv;
        #pragma unroll
        for (int n = 0; n < NST; ++n)
            h[n] = fmaf(h[n], __expf(dv * A[n]), dx * bc[n]);
    }
    size_t base = (size_t)(b * NCH + c) * NST * DIN + d;
    #pragma unroll
    for (int n = 0; n < NST; ++n) hloc[base + (size_t)n * DIN] = h[n];
    ssum[(size_t)(b * NCH + c) * DIN + d] = s;
}

__global__ __launch_bounds__(256)
void scan_part2_kernel(float* __restrict__ hloc, const float* __restrict__ ssum,
                       const float* __restrict__ A_log)
{
    int idx = blockIdx.x * 256 + threadIdx.x;
    int b = idx >> 12;
    int d = idx & (DIN - 1);
    float A[NST], hin[NST];
    #pragma unroll
    for (int n = 0; n < NST; ++n) {
        A[n] = -__expf(A_log[d * NST + n]);
        hin[n] = 0.f;
    }
    for (int c = 0; c < NCH; ++c) {
        size_t base = (size_t)(b * NCH + c) * NST * DIN + d;
        float s = ssum[(size_t)(b * NCH + c) * DIN + d];
        #pragma unroll
        for (int n = 0; n < NST; ++n) {
            float hl = hloc[base + (size_t)n * DIN];
            hloc[base + (size_t)n * DIN] = hin[n];
            hin[n] = fmaf(hin[n], __expf(A[n] * s), hl);
        }
    }
}

__global__ __launch_bounds__(256)
void scan_part3_kernel(const float* __restrict__ delta, float* __restrict__ xcy,
                       const float* __restrict__ xdbl, const float* __restrict__ z,
                       const float* __restrict__ A_log, const float* __restrict__ Dp,
                       const float* __restrict__ hin_buf)
{
    int d = blockIdx.x * 256 + threadIdx.x;
    int c = blockIdx.y;
    int b = blockIdx.z;
    float A[NST], h[NST];
    size_t base = (size_t)(b * NCH + c) * NST * DIN + d;
    #pragma unroll
    for (int n = 0; n < NST; ++n) {
        A[n] = -__expf(A_log[d * NST + n]);
        h[n] = hin_buf[base + (size_t)n * DIN];
    }
    float Dv = Dp[d];
    int tok = b * LSEQ + c * CHUNK;
    for (int t = 0; t < CHUNK; ++t, ++tok) {
        float dv = delta[(size_t)tok * DIN + d];
        float xv = xcy[(size_t)tok * DIN + d];
        float zv = z[(size_t)tok * DIN + d];
        const float* bc = xdbl + (size_t)tok * 160 + RR;
        float dx = dv * xv;
        float y = 0.f;
        #pragma unroll
        for (int n = 0; n < NST; ++n) {
            h[n] = fmaf(h[n], __expf(dv * A[n]), dx * bc[n]);
            y = fmaf(h[n], bc[NST + n], y);
        }
        y = (y + xv * Dv) * (zv * sigmoidf_(zv));
        xcy[(size_t)tok * DIN + d] = y;
    }
}

extern "C" void kernel_launch(void* const* d_in, const int* in_sizes, int n_in,
                              void* d_out, int out_size, void* d_ws, size_t ws_size,
                              hipStream_t stream)
{
    const float* hidden     = (const float*)d_in[0];
    const float* in_proj_w  = (const float*)d_in[1];
    const float* conv_w     = (const float*)d_in[2];
    const float* x_proj_w   = (const float*)d_in[3];
    const float* dt_proj_w  = (const float*)d_in[4];
    const float* dt_bias    = (const float*)d_in[5];
    const float* A_log      = (const float*)d_in[6];
    const float* D_param    = (const float*)d_in[7];
    const float* out_proj_w = (const float*)d_in[8];
    float* out = (float*)d_out;

    // Workspace: 3 x 67.1 MB + 2.6 MB = 204 MB (known-safe footprint)
    const size_t BIG = (size_t)NTOK * DIN * sizeof(float);
    char* ws = (char*)d_ws;
    float* xbuf = (float*)(ws);                              // x -> delta -> y_bf
    float* xc   = (float*)(ws + BIG);                        // w_in_bf -> xc/y -> G3 partial
    float* zbuf = (float*)(ws + 2 * BIG);                    // z -> w_out_bf
    float* xdbl = (float*)(ws + 3 * BIG);                    // 2.6 MB
    float* delta = xbuf;

    // bf16 staging buffers in dead regions:
    unsigned short* w_in_bf  = (unsigned short*)xc;          // dies at conv
    unsigned short* hid_bf   = (unsigned short*)out;         // dies after G1
    unsigned short* y_bf     = (unsigned short*)xbuf;        // after delta dead
    unsigned short* w_out_bf = (unsigned short*)zbuf;        // after z dead

    // d_out scratch (33.5 MB), time-multiplexed:
    //   hid_bf (16.8 MB, steps 0-1) -> kspl partial (21 MB) + dtr/dtw bf16 (21-23 MB)
    //   -> hloc+ssum (17.8 MB, step 5) -> final GEMM output (step 6)
    float* xpart = out;                                          // 21 MB
    unsigned short* dtr_bf = (unsigned short*)(out + (size_t)KSPL * NTOK * 160);  // 1 MB
    unsigned short* dtw_bf = dtr_bf + (size_t)NTOK * RR;                          // 1 MB
    float* hloc  = out;
    float* ssum  = out + (size_t)BB * NCH * NST * DIN;

    // 0) fp32 -> bf16 for GEMM1
    f2bf_kernel<<<8192, 256, 0, stream>>>(in_proj_w, w_in_bf, (2 * DIN * 2048) / 8);
    f2bf_kernel<<<4096, 256, 0, stream>>>(hidden, hid_bf, (NTOK * 2048) / 8);
    // 1) x | z = hidden @ in_proj_w^T  (256^2 8-phase MFMA, fused split-dest)
    //    M=4096, N=8192, K=2048 -> 512 blocks; XCD chunk 8bm x 8bn
    gemm256<2><<<512, 512, 0, stream>>>(hid_bf, w_in_bf, xbuf, 2048, 2048, DIN,
                                        zbuf, 32, 4);
    // 2) xc = silu(causal_conv(x))
    conv_silu_kernel<<<(NTOK * DIN) / 256, 256, 0, stream>>>(xbuf, conv_w, xc);
    // 3) x_dbl = xc @ x_proj_w^T  (K-split fp32 + reduce; reduce also emits dt_r bf16)
    gemm_kspl_kernel<<<dim3(NTOK / 64, KSPL), 256, 0, stream>>>(xc, x_proj_w, xpart);
    kspl_reduce_kernel<<<(NTOK * 160) / 256, 256, 0, stream>>>(xpart, xdbl, dtr_bf);
    // 4) delta = softplus(dt_r @ dt_proj_w^T + bias)  (m97 kernel, K=128)
    f2bf_kernel<<<256, 256, 0, stream>>>(dt_proj_w, dtw_bf, (DIN * RR) / 8);
    gemm_mfma_bt<1><<<dim3(32, 32), 256, 0, stream>>>(dtr_bf, dtw_bf, delta,
                                                      RR, DIN, dt_bias, nullptr);
    // 5) chunked selective scan
    scan_part1_kernel<<<dim3(DIN / 256, NCH, BB), 256, 0, stream>>>(delta, xc, xdbl,
                                                                    A_log, hloc, ssum);
    scan_part2_kernel<<<(BB * DIN) / 256, 256, 0, stream>>>(hloc, ssum, A_log);
    scan_part3_kernel<<<dim3(DIN / 256, NCH, BB), 256, 0, stream>>>(delta, xc, xdbl,
                                                                    zbuf, A_log, D_param, hloc);
    // 5c) convert for final GEMM
    f2bf_kernel<<<8192, 256, 0, stream>>>(xc, y_bf, (NTOK * DIN) / 8);
    f2bf_kernel<<<4096, 256, 0, stream>>>(out_proj_w, w_out_bf, (2048 * DIN) / 8);
    // 6) out = y @ out_proj_w^T  (256^2 8-phase MFMA, split-K=2: 256 blocks,
    //    XCDs 0-3 -> k-half 0 -> out, XCDs 4-7 -> k-half 1 -> partial in xc)
    gemm256<3><<<256, 512, 0, stream>>>(y_bf, w_out_bf, out, 4096, 2048, 2048,
                                        xc, 8, 2);
    add_f4_kernel<<<8192, 256, 0, stream>>>(out, xc, (NTOK * 2048) / 4);
}

// Round 7
// 717.759 us; speedup vs baseline: 1.2590x; 1.2590x over previous
//
#include <hip/hip_runtime.h>
#include <math.h>

// Problem constants
#define DIN   4096
#define NST   16
#define RR    128
#define LSEQ  2048
#define NTOK  4096   // B*L
#define BB    2
#define CHUNK 64
#define NCH   (LSEQ / CHUNK)   // 32
#define KSPL  8                // k-split for skinny GEMM
#define KC    (DIN / KSPL)     // 512

typedef __attribute__((ext_vector_type(8))) short short8;
typedef __attribute__((ext_vector_type(4))) float f32x4;

__device__ __forceinline__ float sigmoidf_(float x) { return 1.f / (1.f + __expf(-x)); }
__device__ __forceinline__ float softplusf_(float x) {
    return fmaxf(x, 0.f) + log1pf(__expf(-fabsf(x)));
}
__device__ __forceinline__ unsigned short f2bf_(float f) {
    unsigned u = __float_as_uint(f);
    return (unsigned short)((u + 0x7FFFu + ((u >> 16) & 1u)) >> 16);   // RNE
}
__device__ __forceinline__ void gld_lds16_(const unsigned short* g, unsigned short* l) {
    __builtin_amdgcn_global_load_lds((const __attribute__((address_space(1))) unsigned int*)g,
                                     (__attribute__((address_space(3))) unsigned int*)l,
                                     16, 0, 0);
}

// fp32 -> bf16 (RNE), 8 elements/thread
__global__ __launch_bounds__(256)
void f2bf_kernel(const float* __restrict__ src, unsigned short* __restrict__ dst, int n8)
{
    int i = blockIdx.x * 256 + threadIdx.x;
    if (i >= n8) return;
    const float4* s = (const float4*)src + 2 * (size_t)i;
    float4 a = s[0], b = s[1];
    union { unsigned short u[8]; uint4 v; } o;
    o.u[0] = f2bf_(a.x); o.u[1] = f2bf_(a.y); o.u[2] = f2bf_(a.z); o.u[3] = f2bf_(a.w);
    o.u[4] = f2bf_(b.x); o.u[5] = f2bf_(b.y); o.u[6] = f2bf_(b.z); o.u[7] = f2bf_(b.w);
    ((uint4*)dst)[i] = o.v;
}

// dst += src, float4-vectorized (split-K reduce for GEMM3)
__global__ __launch_bounds__(256)
void add_f4_kernel(float* __restrict__ dst, const float* __restrict__ src, int n4)
{
    int i = blockIdx.x * 256 + threadIdx.x;
    if (i >= n4) return;
    float4 a = ((const float4*)dst)[i];
    float4 b = ((const float4*)src)[i];
    a.x += b.x; a.y += b.y; a.z += b.z; a.w += b.w;
    ((float4*)dst)[i] = a;
}

// ---- 256x256 4-phase bf16 MFMA GEMM ---------------------------------------
// C[M,N] fp32 = A[M,K] * W[N,K]^T.  BM=BN=256, BK=64, 8 waves (2Mx4N),
// per-wave 128x64 output, 128 KiB double-buffered LDS, 3-bit LDS swizzle
// (0 bank conflicts, R3-verified), counted vmcnt(6), setprio, 2-D XCD chunk.
// R7: 4 phases per K-tile pair (was 8). Each phase: reads-at-top (R3's proven
// register-neutral pattern: aF/bA/bB only, 64 frag VGPR — R6's aG spilled),
// one BAR, lgkmcnt(0), 32 MFMA (two quads), optional vmcnt, one BAR.  Halves
// barrier + drain count per K-tile.  Staging ledger (re-derived, 4-phase):
//   stages: P1 buf1.A1<-t+1 | P2 buf0.{A0,B0,B1}<-t+2 | P3 buf0.A1<-t+2
//           P4 buf1.{A0,B0,B1}<-t+3 ;  checkpoints vmcnt(6) at P2/P4 ends.
//   validity: buf0 tile t fully drained at prev-P4 ckpt (drains prevP2's 6 +
//   prevP3's 2, leaves prevP4's 6); buf1 tile t+1 drained at P2 ckpt (drains
//   prevP4's 6 + P1's 2, leaves P2's 6).  Write-safety: every stage issues
//   >=1 barrier after all waves' reads of its region completed (reads finish
//   before each wave's lgkmcnt; BAR = all arrived).  Prologue: tile0 (8) +
//   tile1 {A0,B0,B1} (6), vmcnt(6) drains tile0.  Final iter PREF=0: P1's
//   buf1.A1 stage unconditional (tile KT-1), vmcnt(0) drains.
// MODE 0: plain. MODE 2: split dest at col DIN -> C2. MODE 3: split-K=2
// (virtual bm rows 0-15 -> k-half 0 -> C, 16-31 -> k-half 1 -> C2).

#define BAR()        asm volatile("s_barrier" ::: "memory")
#define WAIT_LGKM0() asm volatile("s_waitcnt lgkmcnt(0)" ::: "memory")
#define WAIT_VM(n)   asm volatile("s_waitcnt vmcnt(" #n ")" ::: "memory")

// LDS layout (bytes): [0,32K) buf0.A  [32K,64K) buf0.B  [64K,96K) buf1.A  [96K,128K) buf1.B
// A/B region: 256 rows x 64 cols bf16, row stride 128 B, halves of 128 rows (16 KiB).
// Physical col_byte = logical col_byte ^ ((row&7)<<4).  Logical col for a
// fragment read = q*16 + ks*64; per-lane bases co0 (ks=0), co1 = co0^64 (ks=1).

#define RD_A(P, mh) do { _Pragma("unroll") \
  for (int ii = 0; ii < 4; ++ii) { \
      aF[ii][0] = *(const short8*)((P) + (mh)*8192 + ii*2048 + co0); \
      aF[ii][1] = *(const short8*)((P) + (mh)*8192 + ii*2048 + co1); } } while (0)

#define RD_B(P, nh, DST) do { _Pragma("unroll") \
  for (int jj = 0; jj < 2; ++jj) { \
      DST[jj][0] = *(const short8*)((P) + (nh)*4096 + jj*2048 + co0); \
      DST[jj][1] = *(const short8*)((P) + (nh)*4096 + jj*2048 + co1); } } while (0)

#define MFMA_Q(mh, nh, BF) do { __builtin_amdgcn_s_setprio(1); _Pragma("unroll") \
  for (int ii = 0; ii < 4; ++ii) { _Pragma("unroll") \
    for (int jj = 0; jj < 2; ++jj) { _Pragma("unroll") \
      for (int ks = 0; ks < 2; ++ks) \
        acc[(mh)*4+ii][(nh)*2+jj] = __builtin_amdgcn_mfma_f32_16x16x32_bf16( \
            aF[ii][ks], BF[jj][ks], acc[(mh)*4+ii][(nh)*2+jj], 0, 0, 0); } } \
  __builtin_amdgcn_s_setprio(0); } while (0)

// stage one 16B/lane load: half h (128 rows), part l (64 rows), K-tile `tile`
#define STGLD(gbase, sbase, h, l, tile) \
  gld_lds16_(gbase + (size_t)((h)*128 + (l)*64) * K + (size_t)(tile)*64, \
             (unsigned short*)(sbase + (h)*16384 + (l)*8192))

// One main-loop iteration: consumes K-tiles t (buf0, P1-2) and t+1 (buf1, P3-4).
#define ITER(t, PREF) do { \
  /* P1: read buf0 A0,B0,B1 (16); stage buf1.A1<-t+1 (uncond) */ \
  RD_A(pA0, 0); RD_B(pB0c, 0, bA); RD_B(pB0c, 1, bB); \
  STGLD(gA0, sA1, 1, 0, (t)+1); STGLD(gA0, sA1, 1, 1, (t)+1); \
  BAR(); WAIT_LGKM0(); MFMA_Q(0, 0, bA); MFMA_Q(0, 1, bB); BAR(); \
  /* P2: read buf0 A1 (8); stage buf0.{A0,B0,B1}<-t+2; ckpt (buf1 t+1 valid) */ \
  RD_A(pA0, 1); \
  if (PREF) { STGLD(gA0, sA0, 0, 0, (t)+2); STGLD(gA0, sA0, 0, 1, (t)+2); \
              STGLD(gB0, sB0, 0, 0, (t)+2); STGLD(gB0, sB0, 0, 1, (t)+2); \
              STGLD(gB0, sB0, 1, 0, (t)+2); STGLD(gB0, sB0, 1, 1, (t)+2); } \
  BAR(); WAIT_LGKM0(); MFMA_Q(1, 1, bB); MFMA_Q(1, 0, bA); \
  if (PREF) { WAIT_VM(6); } else { WAIT_VM(0); } \
  BAR(); \
  /* P3: read buf1 A0,B0,B1 (16); stage buf0.A1<-t+2 */ \
  RD_A(pA1, 0); RD_B(pB1c, 0, bA); RD_B(pB1c, 1, bB); \
  if (PREF) { STGLD(gA0, sA0, 1, 0, (t)+2); STGLD(gA0, sA0, 1, 1, (t)+2); } \
  BAR(); WAIT_LGKM0(); MFMA_Q(0, 0, bA); MFMA_Q(0, 1, bB); BAR(); \
  /* P4: read buf1 A1 (8); stage buf1.{A0,B0,B1}<-t+3; ckpt (buf0 t+2 valid) */ \
  RD_A(pA1, 1); \
  if (PREF) { STGLD(gA0, sA1, 0, 0, (t)+3); STGLD(gA0, sA1, 0, 1, (t)+3); \
              STGLD(gB0, sB1, 0, 0, (t)+3); STGLD(gB0, sB1, 0, 1, (t)+3); \
              STGLD(gB0, sB1, 1, 0, (t)+3); STGLD(gB0, sB1, 1, 1, (t)+3); } \
  BAR(); WAIT_LGKM0(); MFMA_Q(1, 1, bB); MFMA_Q(1, 0, bA); \
  if (PREF) { WAIT_VM(6); } else { WAIT_VM(0); } \
  BAR(); \
} while (0)

// K = leading dim (row stride) of A/W; KL = K-extent this block accumulates.
template<int MODE>
__global__ __launch_bounds__(512)
void gemm256(const unsigned short* __restrict__ A, const unsigned short* __restrict__ W,
             float* __restrict__ C, int K, int KL, int ldc, float* __restrict__ C2,
             int nbx, int fx)
{
    __shared__ __align__(16) unsigned short sm[65536];   // 128 KiB
    char* smb = (char*)sm;

    const int tid = threadIdx.x;
    const int ln  = tid & 63;
    const int wv  = tid >> 6;     // 0..7
    const int wm  = wv >> 2;      // 0..1  (M direction)
    const int wn  = wv & 3;       // 0..3  (N direction)
    const int m15 = ln & 15;
    const int q   = ln >> 4;

    // 2-D XCD chunking (requires gridDim.x % 8 == 0, nbx % fx == 0)
    const int bid = blockIdx.x;
    const int xcd = bid & 7;
    const int idx = bid >> 3;
    const int cw  = nbx / fx;                  // region width in bn-blocks
    const int chh = (gridDim.x >> 3) / cw;     // region height in bm-blocks
    const int bn_i = (xcd % fx) * cw  + idx % cw;
    int bm_i = (xcd / fx) * chh + idx / cw;
    int kh = 0;
    if (MODE == 3) { kh = bm_i >> 4; bm_i &= 15; }   // split-K=2 (16 bm-blocks/half)
    const int bm  = bm_i << 8;
    const int bn  = bn_i << 8;

    // ds_read bases: 3-bit row swizzle, XOR'd column bases for ks=0/1
    const int co0 = (q * 16) ^ ((m15 & 7) << 4);
    const int co1 = co0 ^ 64;
    const int ra_base = wm * 16384 + m15 * 128;
    const int rb_base = wn * 8192  + m15 * 128;
    const char* pA0  = smb + ra_base;
    const char* pA1  = smb + 65536 + ra_base;
    const char* pB0c = smb + 32768 + rb_base;
    const char* pB1c = smb + 98304 + rb_base;

    // staging: linear LDS dest (base + lane*16), inverse-swizzled global source
    char* sA0 = smb +          tid * 16;
    char* sB0 = smb + 32768  + tid * 16;
    char* sA1 = smb + 65536  + tid * 16;
    char* sB1 = smb + 98304  + tid * 16;
    const int srow  = tid >> 3;                                   // 0..63
    const int secol = (((tid & 7) ^ ((tid >> 3) & 7)) * 8);       // logical col elems
    const unsigned short* gA0 = A + (size_t)(bm + srow) * K + secol + (size_t)kh * KL;
    const unsigned short* gB0 = W + (size_t)(bn + srow) * K + secol + (size_t)kh * KL;

    f32x4  acc[8][4] = {};
    short8 aF[4][2], bA[2][2], bB[2][2];

    const int KT = KL >> 6;   // K-tiles of 64

    // Prologue: tile0 full (8 loads) + tile1 {A0,B0,B1} (6 loads); drain to 6.
    STGLD(gA0, sA0, 0, 0, 0); STGLD(gA0, sA0, 0, 1, 0);
    STGLD(gA0, sA0, 1, 0, 0); STGLD(gA0, sA0, 1, 1, 0);
    STGLD(gB0, sB0, 0, 0, 0); STGLD(gB0, sB0, 0, 1, 0);
    STGLD(gB0, sB0, 1, 0, 0); STGLD(gB0, sB0, 1, 1, 0);
    STGLD(gA0, sA1, 0, 0, 1); STGLD(gA0, sA1, 0, 1, 1);
    STGLD(gB0, sB1, 0, 0, 1); STGLD(gB0, sB1, 0, 1, 1);
    STGLD(gB0, sB1, 1, 0, 1); STGLD(gB0, sB1, 1, 1, 1);
    WAIT_VM(6);
    BAR();

    for (int t = 0; t < KT - 2; t += 2) ITER(t, 1);
    ITER(KT - 2, 0);   // last pair: drains vmcnt at P2/P4

    // Epilogue (C/D map: col = m15-based, row = q*4+r — proven m97 mapping)
    float* Cp = C;
    int bcol = bn;
    if (MODE == 2 && bcol >= DIN) { Cp = C2; bcol -= DIN; }   // block-uniform
    if (MODE == 3 && kh) Cp = C2;                              // split-K partial
    #pragma unroll
    for (int i = 0; i < 8; ++i) {
        int row = bm + wm * 128 + i * 16 + q * 4;
        #pragma unroll
        for (int j = 0; j < 4; ++j) {
            int col = bcol + wn * 64 + j * 16 + m15;
            #pragma unroll
            for (int r = 0; r < 4; ++r)
                Cp[(size_t)(row + r) * ldc + col] = acc[i][j][r];
        }
    }
}

// ---- legacy 128x128 m97-structure MFMA GEMM (kept for the K=128 delta GEMM) --
// MODE 1: C = softplus(C + bias[col]).
template<int MODE>
__global__ __launch_bounds__(256)
void gemm_mfma_bt(const unsigned short* __restrict__ A, const unsigned short* __restrict__ W,
                  float* __restrict__ C, int K, int ldc,
                  const float* __restrict__ bias, float* __restrict__ C2)
{
    __shared__ unsigned short As[128 * 32];
    __shared__ unsigned short Ws[128 * 32];
    const int tid = threadIdx.x;
    const int bm = blockIdx.y << 7;
    int bn = blockIdx.x << 7;

    const int c0 = tid, c1 = tid + 256;
    const unsigned short* ga0 = A + (size_t)(bm + (c0 >> 2)) * K + (c0 & 3) * 8;
    const unsigned short* ga1 = A + (size_t)(bm + (c1 >> 2)) * K + (c1 & 3) * 8;
    const unsigned short* gw0 = W + (size_t)(bn + (c0 >> 2)) * K + (c0 & 3) * 8;
    const unsigned short* gw1 = W + (size_t)(bn + (c1 >> 2)) * K + (c1 & 3) * 8;
    unsigned short* la0 = &As[c0 * 8];
    unsigned short* la1 = &As[c1 * 8];
    unsigned short* lw0 = &Ws[c0 * 8];
    unsigned short* lw1 = &Ws[c1 * 8];

    const int ln  = tid & 63;
    const int wv  = tid >> 6;
    const int wm  = (wv >> 1) << 6;
    const int wn  = (wv & 1) << 6;
    const int m15 = ln & 15;
    const int q   = ln >> 4;

    f32x4 acc[4][4] = {};

    for (int k0 = 0; k0 < K; k0 += 32) {
        __syncthreads();
        gld_lds16_(ga0, la0); gld_lds16_(ga1, la1);
        gld_lds16_(gw0, lw0); gld_lds16_(gw1, lw1);
        ga0 += 32; ga1 += 32; gw0 += 32; gw1 += 32;
        __syncthreads();
        short8 af[4], wf[4];
        #pragma unroll
        for (int i = 0; i < 4; ++i)
            af[i] = *(const short8*)&As[(wm + i * 16 + m15) * 32 + q * 8];
        #pragma unroll
        for (int j = 0; j < 4; ++j)
            wf[j] = *(const short8*)&Ws[(wn + j * 16 + m15) * 32 + q * 8];
        #pragma unroll
        for (int i = 0; i < 4; ++i)
            #pragma unroll
            for (int j = 0; j < 4; ++j)
                acc[i][j] = __builtin_amdgcn_mfma_f32_16x16x32_bf16(af[i], wf[j],
                                                                    acc[i][j], 0, 0, 0);
    }

    float* Cp = C;
    if (MODE == 2 && bn >= DIN) { Cp = C2; bn -= DIN; }

    #pragma unroll
    for (int i = 0; i < 4; ++i)
        #pragma unroll
        for (int j = 0; j < 4; ++j) {
            int col = bn + wn + j * 16 + m15;
            #pragma unroll
            for (int r = 0; r < 4; ++r) {
                int row = bm + wm + i * 16 + q * 4 + r;
                float v = acc[i][j][r];
                if (MODE == 1) v = softplusf_(v + bias[col]);
                Cp[(size_t)row * ldc + col] = v;
            }
        }
}

// ---- K-split skinny GEMM: partial[kspl][M][160] = A[M, kc] * W[160, kc]^T --
__global__ __launch_bounds__(256)
void gemm_kspl_kernel(const float* __restrict__ A, const float* __restrict__ W,
                      float* __restrict__ partial)
{
    __shared__ float As[16][66];
    __shared__ float Ws[16][162];
    const int tid = threadIdx.x;
    const int tx = tid & 15;
    const int ty = tid >> 4;
    const int bm = blockIdx.x << 6;
    const int k0 = blockIdx.y * KC;

    float acc[4][10] = {};

    for (int kt = 0; kt < KC; kt += 16) {
        float2 a2[2];
        #pragma unroll
        for (int i = 0; i < 2; ++i) {
            int idx = tid + 256 * i;
            int row = idx >> 3, kofs = (idx & 7) * 2;
            a2[i] = *(const float2*)&A[(size_t)(bm + row) * DIN + k0 + kt + kofs];
        }
        float2 w2[5];
        #pragma unroll
        for (int i = 0; i < 5; ++i) {
            int idx = tid + 256 * i;
            int wrow = idx >> 3, wk = (idx & 7) * 2;
            w2[i] = *(const float2*)&W[(size_t)wrow * DIN + k0 + kt + wk];
        }
        __syncthreads();
        #pragma unroll
        for (int i = 0; i < 2; ++i) {
            int idx = tid + 256 * i;
            int row = idx >> 3, kofs = (idx & 7) * 2;
            As[kofs][row] = a2[i].x; As[kofs + 1][row] = a2[i].y;
        }
        #pragma unroll
        for (int i = 0; i < 5; ++i) {
            int idx = tid + 256 * i;
            int wrow = idx >> 3, wk = (idx & 7) * 2;
            Ws[wk][wrow] = w2[i].x; Ws[wk + 1][wrow] = w2[i].y;
        }
        __syncthreads();
        #pragma unroll
        for (int kk = 0; kk < 16; ++kk) {
            float2 av0 = *(const float2*)&As[kk][ty * 4];
            float2 av1 = *(const float2*)&As[kk][ty * 4 + 2];
            float a[4] = {av0.x, av0.y, av1.x, av1.y};
            float w[10];
            #pragma unroll
            for (int j = 0; j < 5; ++j) {
                float2 wv = *(const float2*)&Ws[kk][tx * 10 + 2 * j];
                w[2 * j] = wv.x; w[2 * j + 1] = wv.y;
            }
            #pragma unroll
            for (int i = 0; i < 4; ++i)
                #pragma unroll
                for (int j = 0; j < 10; ++j)
                    acc[i][j] = fmaf(a[i], w[j], acc[i][j]);
        }
        __syncthreads();
    }

    float* po = partial + (size_t)blockIdx.y * NTOK * 160;
    #pragma unroll
    for (int i = 0; i < 4; ++i) {
        int r = bm + ty * 4 + i;
        #pragma unroll
        for (int j = 0; j < 5; ++j)
            *(float2*)&po[(size_t)r * 160 + tx * 10 + 2 * j] =
                make_float2(acc[i][2 * j], acc[i][2 * j + 1]);
    }
}

// sum KSPL partials -> xdbl; also emit bf16 copy of dt_r (cols < 128)
__global__ __launch_bounds__(256)
void kspl_reduce_kernel(const float* __restrict__ partial, float* __restrict__ xdbl,
                        unsigned short* __restrict__ dtr)
{
    int idx = blockIdx.x * 256 + threadIdx.x;   // over NTOK*160
    float s = 0.f;
    #pragma unroll
    for (int k = 0; k < KSPL; ++k)
        s += partial[(size_t)k * NTOK * 160 + idx];
    xdbl[idx] = s;
    int row = idx / 160;
    int col = idx - row * 160;
    if (col < RR) dtr[(size_t)row * RR + col] = f2bf_(s);
}

// Causal depthwise conv (K=4) + SiLU.
__global__ __launch_bounds__(256)
void conv_silu_kernel(const float* __restrict__ x, const float* __restrict__ cw,
                      float* __restrict__ xc)
{
    int idx = blockIdx.x * 256 + threadIdx.x;
    int d = idx & (DIN - 1);
    int tok = idx >> 12;
    int t = tok & (LSEQ - 1);
    float w0 = cw[d * 4 + 0], w1 = cw[d * 4 + 1];
    float w2 = cw[d * 4 + 2], w3 = cw[d * 4 + 3];
    const float* xp = x + (size_t)tok * DIN + d;
    float acc = w3 * xp[0];
    if (t >= 1) acc = fmaf(w2, xp[-DIN], acc);
    if (t >= 2) acc = fmaf(w1, xp[-2 * DIN], acc);
    if (t >= 3) acc = fmaf(w0, xp[-3 * DIN], acc);
    xc[idx] = acc * sigmoidf_(acc);
}

// ---- Chunked parallel selective scan --------------------------------------
__global__ __launch_bounds__(256)
void scan_part1_kernel(const float* __restrict__ delta, const float* __restrict__ xc,
                       const float* __restrict__ xdbl, const float* __restrict__ A_log,
                       float* __restrict__ hloc, float* __restrict__ ssum)
{
    int d = blockIdx.x * 256 + threadIdx.x;
    int c = blockIdx.y;
    int b = blockIdx.z;
    float A[NST], h[NST];
    #pragma unroll
    for (int n = 0; n < NST; ++n) {
        A[n] = -__expf(A_log[d * NST + n]);
        h[n] = 0.f;
    }
    float s = 0.f;
    int tok = b * LSEQ + c * CHUNK;
    for (int t = 0; t < CHUNK; ++t, ++tok) {
        float dv = delta[(size_t)tok * DIN + d];
        float xv = xc[(size_t)tok * DIN + d];
        const float* bc = xdbl + (size_t)tok * 160 + RR;
        float dx = dv * xv;
        s += dv;
        #pragma unroll
        for (int n = 0; n < NST; ++n)
            h[n] = fmaf(h[n], __expf(dv * A[n]), dx * bc[n]);
    }
    size_t base = (size_t)(b * NCH + c) * NST * DIN + d;
    #pragma unroll
    for (int n = 0; n < NST; ++n) hloc[base + (size_t)n * DIN] = h[n];
    ssum[(size_t)(b * NCH + c) * DIN + d] = s;
}

__global__ __launch_bounds__(256)
void scan_part2_kernel(float* __restrict__ hloc, const float* __restrict__ ssum,
                       const float* __restrict__ A_log)
{
    int idx = blockIdx.x * 256 + threadIdx.x;
    int b = idx >> 12;
    int d = idx & (DIN - 1);
    float A[NST], hin[NST];
    #pragma unroll
    for (int n = 0; n < NST; ++n) {
        A[n] = -__expf(A_log[d * NST + n]);
        hin[n] = 0.f;
    }
    for (int c = 0; c < NCH; ++c) {
        size_t base = (size_t)(b * NCH + c) * NST * DIN + d;
        float s = ssum[(size_t)(b * NCH + c) * DIN + d];
        #pragma unroll
        for (int n = 0; n < NST; ++n) {
            float hl = hloc[base + (size_t)n * DIN];
            hloc[base + (size_t)n * DIN] = hin[n];
            hin[n] = fmaf(hin[n], __expf(A[n] * s), hl);
        }
    }
}

__global__ __launch_bounds__(256)
void scan_part3_kernel(const float* __restrict__ delta, float* __restrict__ xcy,
                       const float* __restrict__ xdbl, const float* __restrict__ z,
                       const float* __restrict__ A_log, const float* __restrict__ Dp,
                       const float* __restrict__ hin_buf)
{
    int d = blockIdx.x * 256 + threadIdx.x;
    int c = blockIdx.y;
    int b = blockIdx.z;
    float A[NST], h[NST];
    size_t base = (size_t)(b * NCH + c) * NST * DIN + d;
    #pragma unroll
    for (int n = 0; n < NST; ++n) {
        A[n] = -__expf(A_log[d * NST + n]);
        h[n] = hin_buf[base + (size_t)n * DIN];
    }
    float Dv = Dp[d];
    int tok = b * LSEQ + c * CHUNK;
    for (int t = 0; t < CHUNK; ++t, ++tok) {
        float dv = delta[(size_t)tok * DIN + d];
        float xv = xcy[(size_t)tok * DIN + d];
        float zv = z[(size_t)tok * DIN + d];
        const float* bc = xdbl + (size_t)tok * 160 + RR;
        float dx = dv * xv;
        float y = 0.f;
        #pragma unroll
        for (int n = 0; n < NST; ++n) {
            h[n] = fmaf(h[n], __expf(dv * A[n]), dx * bc[n]);
            y = fmaf(h[n], bc[NST + n], y);
        }
        y = (y + xv * Dv) * (zv * sigmoidf_(zv));
        xcy[(size_t)tok * DIN + d] = y;
    }
}

extern "C" void kernel_launch(void* const* d_in, const int* in_sizes, int n_in,
                              void* d_out, int out_size, void* d_ws, size_t ws_size,
                              hipStream_t stream)
{
    const float* hidden     = (const float*)d_in[0];
    const float* in_proj_w  = (const float*)d_in[1];
    const float* conv_w     = (const float*)d_in[2];
    const float* x_proj_w   = (const float*)d_in[3];
    const float* dt_proj_w  = (const float*)d_in[4];
    const float* dt_bias    = (const float*)d_in[5];
    const float* A_log      = (const float*)d_in[6];
    const float* D_param    = (const float*)d_in[7];
    const float* out_proj_w = (const float*)d_in[8];
    float* out = (float*)d_out;

    // Workspace: 3 x 67.1 MB + 2.6 MB = 204 MB (known-safe footprint)
    const size_t BIG = (size_t)NTOK * DIN * sizeof(float);
    char* ws = (char*)d_ws;
    float* xbuf = (float*)(ws);                              // x -> delta -> y_bf
    float* xc   = (float*)(ws + BIG);                        // w_in_bf -> xc/y -> G3 partial
    float* zbuf = (float*)(ws + 2 * BIG);                    // z -> w_out_bf
    float* xdbl = (float*)(ws + 3 * BIG);                    // 2.6 MB
    float* delta = xbuf;

    // bf16 staging buffers in dead regions:
    unsigned short* w_in_bf  = (unsigned short*)xc;          // dies at conv
    unsigned short* hid_bf   = (unsigned short*)out;         // dies after G1
    unsigned short* y_bf     = (unsigned short*)xbuf;        // after delta dead
    unsigned short* w_out_bf = (unsigned short*)zbuf;        // after z dead

    // d_out scratch (33.5 MB), time-multiplexed:
    //   hid_bf (16.8 MB, steps 0-1) -> kspl partial (21 MB) + dtr/dtw bf16 (21-23 MB)
    //   -> hloc+ssum (17.8 MB, step 5) -> final GEMM output (step 6)
    float* xpart = out;                                          // 21 MB
    unsigned short* dtr_bf = (unsigned short*)(out + (size_t)KSPL * NTOK * 160);  // 1 MB
    unsigned short* dtw_bf = dtr_bf + (size_t)NTOK * RR;                          // 1 MB
    float* hloc  = out;
    float* ssum  = out + (size_t)BB * NCH * NST * DIN;

    // 0) fp32 -> bf16 for GEMM1
    f2bf_kernel<<<8192, 256, 0, stream>>>(in_proj_w, w_in_bf, (2 * DIN * 2048) / 8);
    f2bf_kernel<<<4096, 256, 0, stream>>>(hidden, hid_bf, (NTOK * 2048) / 8);
    // 1) x | z = hidden @ in_proj_w^T  (256^2 4-phase MFMA, fused split-dest)
    //    M=4096, N=8192, K=2048 -> 512 blocks; XCD chunk 8bm x 8bn
    gemm256<2><<<512, 512, 0, stream>>>(hid_bf, w_in_bf, xbuf, 2048, 2048, DIN,
                                        zbuf, 32, 4);
    // 2) xc = silu(causal_conv(x))
    conv_silu_kernel<<<(NTOK * DIN) / 256, 256, 0, stream>>>(xbuf, conv_w, xc);
    // 3) x_dbl = xc @ x_proj_w^T  (K-split fp32 + reduce; reduce also emits dt_r bf16)
    gemm_kspl_kernel<<<dim3(NTOK / 64, KSPL), 256, 0, stream>>>(xc, x_proj_w, xpart);
    kspl_reduce_kernel<<<(NTOK * 160) / 256, 256, 0, stream>>>(xpart, xdbl, dtr_bf);
    // 4) delta = softplus(dt_r @ dt_proj_w^T + bias)  (m97 kernel, K=128)
    f2bf_kernel<<<256, 256, 0, stream>>>(dt_proj_w, dtw_bf, (DIN * RR) / 8);
    gemm_mfma_bt<1><<<dim3(32, 32), 256, 0, stream>>>(dtr_bf, dtw_bf, delta,
                                                      RR, DIN, dt_bias, nullptr);
    // 5) chunked selective scan
    scan_part1_kernel<<<dim3(DIN / 256, NCH, BB), 256, 0, stream>>>(delta, xc, xdbl,
                                                                    A_log, hloc, ssum);
    scan_part2_kernel<<<(BB * DIN) / 256, 256, 0, stream>>>(hloc, ssum, A_log);
    scan_part3_kernel<<<dim3(DIN / 256, NCH, BB), 256, 0, stream>>>(delta, xc, xdbl,
                                                                    zbuf, A_log, D_param, hloc);
    // 5c) convert for final GEMM
    f2bf_kernel<<<8192, 256, 0, stream>>>(xc, y_bf, (NTOK * DIN) / 8);
    f2bf_kernel<<<4096, 256, 0, stream>>>(out_proj_w, w_out_bf, (2048 * DIN) / 8);
    // 6) out = y @ out_proj_w^T  (256^2 4-phase MFMA, split-K=2: 256 blocks,
    //    XCDs 0-3 -> k-half 0 -> out, XCDs 4-7 -> k-half 1 -> partial in xc)
    gemm256<3><<<256, 512, 0, stream>>>(y_bf, w_out_bf, out, 4096, 2048, 2048,
                                        xc, 8, 2);
    add_f4_kernel<<<8192, 256, 0, stream>>>(out, xc, (NTOK * 2048) / 4);
}